// Round 7
// baseline (134.310 us; speedup 1.0000x reference)
//
#include <hip/hip_runtime.h>
#include <stdint.h>

#define KN 9
#define HH 64
#define WW 64
#define CC 128
#define FF 128
#define TM 32      // pixels per block (half an image row)
#define NT 256     // threads per block (4 waves)
#define LDK 136    // padded LDS K-stride (bf16 elements)

typedef __bf16 bf16x8 __attribute__((ext_vector_type(8)));
typedef float f32x4 __attribute__((ext_vector_type(4)));
typedef float f32x2 __attribute__((ext_vector_type(2)));
typedef unsigned short us8 __attribute__((ext_vector_type(8)));
typedef unsigned short us4 __attribute__((ext_vector_type(4)));

// Reference tap layout (verified R3): stack(meshgrid(ij)).reshape(-1,2) pairs
// the C-order flatten of (2,3,3) across the I/J boundary:
//   taps = (0,0)(0,1)(1,1)(2,2)(2,0)(1,2)(0,1)(2,0)(1,2)
__constant__ float c_init_i[KN] = {0.f,0.f,1.f,2.f,2.f,1.f,0.f,2.f,1.f};
__constant__ float c_init_j[KN] = {0.f,1.f,1.f,2.f,0.f,2.f,1.f,0.f,2.f};

static __device__ inline unsigned short f2bf(float f) {
    union { float f; unsigned u; } v; v.f = f;
    unsigned r = v.u + 0x7fffu + ((v.u >> 16) & 1u);  // RNE
    return (unsigned short)(r >> 16);
}

// Transpose + quantize W: (KN, C, F) fp32 -> Wt (KN, F, C) bf16.
// LDS 32x32 tile transpose: coalesced reads AND writes (R6-verified).
__global__ void wt_kernel(const float* __restrict__ Wk, unsigned short* __restrict__ Wt) {
    __shared__ unsigned short t[32][33];
    const int tid = threadIdx.x;
    const int n  = blockIdx.x >> 4;
    const int tf = blockIdx.x & 3;
    const int tc = (blockIdx.x >> 2) & 3;
    const int g  = tid >> 5;
    const int l  = tid & 31;
#pragma unroll
    for (int r = 0; r < 4; ++r) {
        int cl = g * 4 + r;
        t[cl][l] = f2bf(Wk[(n << 14) + ((tc * 32 + cl) << 7) + (tf * 32 + l)]);
    }
    __syncthreads();
#pragma unroll
    for (int r = 0; r < 4; ++r) {
        int fl = g * 4 + r;
        Wt[(n << 14) + ((tf * 32 + fl) << 7) + (tc * 32 + l)] = t[l][fl];
    }
}

__launch_bounds__(NT, 4)   // 4 waves/SIMD -> <=128 VGPR -> 4 blocks/CU
__global__ void deform_kernel(const float* __restrict__ xin,
                              const float* __restrict__ off,
                              const unsigned short* __restrict__ Wt,
                              const float* __restrict__ bias,
                              float* __restrict__ out) {
    __shared__ unsigned short As[2][TM][LDK];  // double-buffered deform tile
    __shared__ int   sO[4][KN][TM];            // 4 corner element offsets
    __shared__ float sF[2][KN][TM];            // fy, fx
    // 17408 + 4608 + 2304 = 24320 B -> 4 blocks/CU (VGPR-capped at 4 waves/SIMD)

    const int tid = threadIdx.x;
    // XCD swizzle (verified R5: FETCH 196->10.5 MB): image b -> XCD b.
    const int bb   = blockIdx.x & 7;
    const int idx  = blockIdx.x >> 3;      // 0..127
    const int hh   = idx >> 1;
    const int half = idx & 1;
    const int pix0 = (bb << 12) + (hh << 6) + (half << 5);

    // ---- setup: clipped coords -> 4 corner offsets + fy/fx, once per (p,n) ----
    for (int t = tid; t < TM * KN; t += NT) {
        int p = t & (TM - 1);
        int n = t >> 5;
        const float* op = off + (size_t)(pix0 + p) * (2 * KN) + 2 * n;
        float y = (float)(hh - 1) + c_init_i[n] + op[0];
        float x = (float)(half * 32 + p - 1) + c_init_j[n] + op[1];
        y = fminf(fmaxf(y, 0.f), 63.f);
        x = fminf(fmaxf(x, 0.f), 63.f);
        float fy0 = floorf(y), fx0 = floorf(x);
        int y0 = (int)fy0, x0 = (int)fx0;
        int y1 = (int)ceilf(y), x1 = (int)ceilf(x);
        sO[0][n][p] = ((y0 << 6) + x0) << 7;   // lt
        sO[1][n][p] = ((y1 << 6) + x0) << 7;   // rt (y1,x0) per TF coords_rt
        sO[2][n][p] = ((y0 << 6) + x1) << 7;   // lb (y0,x1) per TF coords_lb
        sO[3][n][p] = ((y1 << 6) + x1) << 7;   // rb
        sF[0][n][p] = y - fy0;
        sF[1][n][p] = x - fx0;
    }
    __syncthreads();

    const int wave = tid >> 6;
    const int lane = tid & 63;
    const int quad = lane >> 4;
    const int col  = lane & 15;
    const int ntb  = wave * 32;          // this wave's 32 filters

    f32x4 acc[2][2];
#pragma unroll
    for (int a = 0; a < 2; ++a)
#pragma unroll
        for (int b = 0; b < 2; ++b) acc[a][b] = (f32x4){0.f, 0.f, 0.f, 0.f};

    const float* bbase = xin + ((size_t)bb << 19);

    // issue 4 corner loads for gather item k of tap n (lanes 0-31 share p -> LDS broadcast)
    auto issueA = [&](int n, int k, float4* pf) {
        int i  = tid + k * NT;
        int p  = i >> 5;
        int cg = (i & 31) * 4;
        const float* bp = bbase + cg;
        pf[0] = *(const float4*)(bp + sO[0][n][p]);
        pf[1] = *(const float4*)(bp + sO[1][n][p]);
        pf[2] = *(const float4*)(bp + sO[2][n][p]);
        pf[3] = *(const float4*)(bp + sO[3][n][p]);
    };
    // bilinear interp (float2 halves -> v_pk_fma) + pack to As
    auto consumeA = [&](int n, int k, const float4* pf, int cur) {
        int i  = tid + k * NT;
        int p  = i >> 5;
        int cg = (i & 31) * 4;
        float fy = sF[0][n][p], fx = sF[1][n][p];
        f32x2 fy2 = {fy, fy}, fx2 = {fx, fx};
        f32x2 lt0 = {pf[0].x, pf[0].y}, lt1 = {pf[0].z, pf[0].w};
        f32x2 rt0 = {pf[1].x, pf[1].y}, rt1 = {pf[1].z, pf[1].w};
        f32x2 lb0 = {pf[2].x, pf[2].y}, lb1 = {pf[2].z, pf[2].w};
        f32x2 rb0 = {pf[3].x, pf[3].y}, rb1 = {pf[3].z, pf[3].w};
        f32x2 vt0 = lt0 + (rt0 - lt0) * fy2;
        f32x2 vt1 = lt1 + (rt1 - lt1) * fy2;
        f32x2 vb0 = lb0 + (rb0 - lb0) * fy2;
        f32x2 vb1 = lb1 + (rb1 - lb1) * fy2;
        f32x2 r0 = vt0 + (vb0 - vt0) * fx2;
        f32x2 r1 = vt1 + (vb1 - vt1) * fx2;
        us4 pk;
        pk.x = f2bf(r0.x); pk.y = f2bf(r0.y); pk.z = f2bf(r1.x); pk.w = f2bf(r1.y);
        *(us4*)&As[cur][p][cg] = pk;
    };
    // per-lane B fragments straight from L2-resident Wt (no LDS)
    auto loadB = [&](int n, us8* bq) {
        const unsigned short* Wn = Wt + (n << 14);
#pragma unroll
        for (int sub = 0; sub < 2; ++sub)
#pragma unroll
            for (int ks = 0; ks < 4; ++ks)
                bq[sub * 4 + ks] = *(const us8*)(Wn + (ntb + sub * 16 + col) * CC + ks * 32 + quad * 8);
    };

    // ---- prologue ----
    float4 pA0[4], pA1[4];
    us8 bcur[8], bnxt[8];
    issueA(0, 0, pA0);
    issueA(0, 1, pA1);
    loadB(0, bcur);

    for (int n = 0; n < KN; ++n) {
        const int cur = n & 1;
        float4 pA2[4], pA3[4];
        issueA(n, 2, pA2);
        issueA(n, 3, pA3);
        consumeA(n, 0, pA0, cur);
        consumeA(n, 1, pA1, cur);
        consumeA(n, 2, pA2, cur);
        consumeA(n, 3, pA3, cur);
        if (n + 1 < KN) {          // prefetch next tap: flies under MFMA phase
            issueA(n + 1, 0, pA0);
            issueA(n + 1, 1, pA1);
            loadB(n + 1, bnxt);
        }
        __syncthreads();           // As[cur] ready (single barrier per tap)

        // ---- MFMA: 32(M) x 32(N) wave tile, 4 K-steps of 32 ----
#pragma unroll
        for (int ks = 0; ks < 4; ++ks) {
            bf16x8 a0 = __builtin_bit_cast(bf16x8, *(const us8*)(&As[cur][col][ks * 32 + quad * 8]));
            bf16x8 a1 = __builtin_bit_cast(bf16x8, *(const us8*)(&As[cur][16 + col][ks * 32 + quad * 8]));
            bf16x8 b0 = __builtin_bit_cast(bf16x8, bcur[ks]);
            bf16x8 b1 = __builtin_bit_cast(bf16x8, bcur[4 + ks]);
            acc[0][0] = __builtin_amdgcn_mfma_f32_16x16x32_bf16(a0, b0, acc[0][0], 0, 0, 0);
            acc[0][1] = __builtin_amdgcn_mfma_f32_16x16x32_bf16(a0, b1, acc[0][1], 0, 0, 0);
            acc[1][0] = __builtin_amdgcn_mfma_f32_16x16x32_bf16(a1, b0, acc[1][0], 0, 0, 0);
            acc[1][1] = __builtin_amdgcn_mfma_f32_16x16x32_bf16(a1, b1, acc[1][1], 0, 0, 0);
        }
#pragma unroll
        for (int q = 0; q < 8; ++q) bcur[q] = bnxt[q];
        // no trailing barrier: tap n+2's writes (other buffer half) are fenced
        // by barrier n+1 -> safe with double-buffered As.
    }

    // ---- epilogue: C/D layout col=lane&15, row=quad*4+reg (HW-verified) ----
#pragma unroll
    for (int b = 0; b < 2; ++b) {
        int f = ntb + b * 16 + col;
        float bv = bias[f];
#pragma unroll
        for (int a = 0; a < 2; ++a) {
#pragma unroll
            for (int r = 0; r < 4; ++r) {
                int pr = pix0 + a * 16 + quad * 4 + r;
                out[(size_t)pr * FF + f] = acc[a][b][r] + bv;
            }
        }
    }
}

extern "C" void kernel_launch(void* const* d_in, const int* in_sizes, int n_in,
                              void* d_out, int out_size, void* d_ws, size_t ws_size,
                              hipStream_t stream) {
    const float* x    = (const float*)d_in[0];
    const float* off  = (const float*)d_in[1];
    const float* Wk   = (const float*)d_in[2];
    const float* bias = (const float*)d_in[3];
    float* out = (float*)d_out;
    unsigned short* Wt = (unsigned short*)d_ws;  // 9*128*128 bf16 = 294912 B

    wt_kernel<<<KN * 16, 256, 0, stream>>>(Wk, Wt);
    deform_kernel<<<(8 * HH * WW) / TM, NT, 0, stream>>>(x, off, Wt, bias, out);
}

// Round 8
// 128.485 us; speedup vs baseline: 1.0453x; 1.0453x over previous
//
#include <hip/hip_runtime.h>
#include <stdint.h>

#define KN 9
#define HH 64
#define WW 64
#define CC 128
#define FF 128
#define TM 64      // pixels per block (one full image row)
#define NT 512     // threads per block (8 waves)
#define LDK 136    // padded LDS K-stride (bf16 elements; 272B keeps 16B align)

typedef __bf16 bf16x8 __attribute__((ext_vector_type(8)));
typedef float f32x4 __attribute__((ext_vector_type(4)));
typedef unsigned short us8 __attribute__((ext_vector_type(8)));
typedef unsigned short us4 __attribute__((ext_vector_type(4)));

// Reference tap layout (verified R3): stack(meshgrid(ij)).reshape(-1,2) pairs
// the C-order flatten of (2,3,3) across the I/J boundary:
//   taps = (0,0)(0,1)(1,1)(2,2)(2,0)(1,2)(0,1)(2,0)(1,2)
__constant__ float c_init_i[KN] = {0.f,0.f,1.f,2.f,2.f,1.f,0.f,2.f,1.f};
__constant__ float c_init_j[KN] = {0.f,1.f,1.f,2.f,0.f,2.f,1.f,0.f,2.f};

static __device__ inline unsigned short f2bf(float f) {
    union { float f; unsigned u; } v; v.f = f;
    unsigned r = v.u + 0x7fffu + ((v.u >> 16) & 1u);  // RNE
    return (unsigned short)(r >> 16);
}

// Transpose + quantize W: (KN, C, F) fp32 -> Wt (KN, F, C) bf16.
// LDS 32x32 tile transpose: coalesced reads AND writes (R6-verified).
__global__ void wt_kernel(const float* __restrict__ Wk, unsigned short* __restrict__ Wt) {
    __shared__ unsigned short t[32][33];
    const int tid = threadIdx.x;
    const int n  = blockIdx.x >> 4;
    const int tf = blockIdx.x & 3;
    const int tc = (blockIdx.x >> 2) & 3;
    const int g  = tid >> 5;
    const int l  = tid & 31;
#pragma unroll
    for (int r = 0; r < 4; ++r) {
        int cl = g * 4 + r;
        t[cl][l] = f2bf(Wk[(n << 14) + ((tc * 32 + cl) << 7) + (tf * 32 + l)]);
    }
    __syncthreads();
#pragma unroll
    for (int r = 0; r < 4; ++r) {
        int fl = g * 4 + r;
        Wt[(n << 14) + ((tf * 32 + fl) << 7) + (tc * 32 + l)] = t[l][fl];
    }
}

__launch_bounds__(NT, 4)   // hard cap 128 VGPR (no spill risk); 3 blocks/CU if <=85
__global__ void deform_kernel(const float* __restrict__ xin,
                              const float* __restrict__ off,
                              const unsigned short* __restrict__ Wt,
                              const float* __restrict__ bias,
                              float* __restrict__ out) {
    __shared__ unsigned short As[2][TM][LDK];  // double-buffered deform tile
    __shared__ float cY[TM][KN];
    __shared__ float cX[TM][KN];
    // 2*17408 + 2304 + 2304 = 39424 B -> 4 blocks/CU by LDS

    const int tid = threadIdx.x;
    // XCD swizzle (verified R5: FETCH 196->10.5 MB): image b -> XCD b.
    const int bb   = blockIdx.x & 7;
    const int hh   = blockIdx.x >> 3;
    const int pix0 = (bb << 12) + (hh << 6);

    for (int t = tid; t < TM * KN; t += NT) {
        int p = t & (TM - 1);
        int n = t >> 6;
        const float* op = off + (size_t)(pix0 + p) * (2 * KN) + 2 * n;
        float y = (float)(hh - 1) + c_init_i[n] + op[0];
        float x = (float)(p - 1) + c_init_j[n] + op[1];
        cY[p][n] = fminf(fmaxf(y, 0.f), 63.f);
        cX[p][n] = fminf(fmaxf(x, 0.f), 63.f);
    }
    __syncthreads();

    const int wave = tid >> 6;
    const int lane = tid & 63;
    const int quad = lane >> 4;
    const int col  = lane & 15;
    const int mtile = (wave & 1) * 32;   // 2 M-supertiles of 32 pixels
    const int ntile = (wave >> 1) * 32;  // 4 N-supertiles of 32 filters

    f32x4 acc[2][2];
#pragma unroll
    for (int a = 0; a < 2; ++a)
#pragma unroll
        for (int b = 0; b < 2; ++b) acc[a][b] = (f32x4){0.f, 0.f, 0.f, 0.f};

    const float* bbase = xin + ((size_t)bb << 19);

    // issue the 4 corner loads for gather item k of tap n (no wait)
    auto issueA = [&](int n, int k, float4* pf) {
        int i  = tid + k * NT;
        int p  = i >> 5;
        int cg = (i & 31) * 4;
        float y = cY[p][n], x = cX[p][n];
        int y0 = (int)floorf(y), x0 = (int)floorf(x);
        int y1 = (int)ceilf(y),  x1 = (int)ceilf(x);
        pf[0] = *(const float4*)(bbase + ((((y0 << 6) + x0) << 7) + cg));
        pf[1] = *(const float4*)(bbase + ((((y1 << 6) + x0) << 7) + cg));
        pf[2] = *(const float4*)(bbase + ((((y0 << 6) + x1) << 7) + cg));
        pf[3] = *(const float4*)(bbase + ((((y1 << 6) + x1) << 7) + cg));
    };
    // interp prefetched corners and write As[cur]
    auto consumeA = [&](int n, int k, const float4* pf, int cur) {
        int i  = tid + k * NT;
        int p  = i >> 5;
        int cg = (i & 31) * 4;
        float y = cY[p][n], x = cX[p][n];
        float fy = y - floorf(y), fx = x - floorf(x);
        float r0, r1, r2, r3;
        { float vt = pf[0].x + (pf[1].x - pf[0].x) * fy; float vb = pf[2].x + (pf[3].x - pf[2].x) * fy; r0 = vt + (vb - vt) * fx; }
        { float vt = pf[0].y + (pf[1].y - pf[0].y) * fy; float vb = pf[2].y + (pf[3].y - pf[2].y) * fy; r1 = vt + (vb - vt) * fx; }
        { float vt = pf[0].z + (pf[1].z - pf[0].z) * fy; float vb = pf[2].z + (pf[3].z - pf[2].z) * fy; r2 = vt + (vb - vt) * fx; }
        { float vt = pf[0].w + (pf[1].w - pf[0].w) * fy; float vb = pf[2].w + (pf[3].w - pf[2].w) * fy; r3 = vt + (vb - vt) * fx; }
        us4 pk;
        pk.x = f2bf(r0); pk.y = f2bf(r1); pk.z = f2bf(r2); pk.w = f2bf(r3);
        *(us4*)&As[cur][p][cg] = pk;
    };

    for (int n = 0; n < KN; ++n) {
        const int cur = n & 1;
        // ---- gather phase: interleaved issue/consume (transient registers only) ----
        float4 pf0[4], pf1[4], pf2[4], pf3[4];
        issueA(n, 0, pf0);
        issueA(n, 1, pf1);
        consumeA(n, 0, pf0, cur);
        issueA(n, 2, pf2);
        consumeA(n, 1, pf1, cur);
        issueA(n, 3, pf3);
        consumeA(n, 2, pf2, cur);
        consumeA(n, 3, pf3, cur);

        // ---- B fragments straight from L2-resident Wt (no LDS staging) ----
        // issued BEFORE the barrier so they fly during the barrier wait;
        // transient within this iteration (no cross-iteration liveness).
        us8 bq[8];
        const unsigned short* Wn = Wt + (n << 14);
#pragma unroll
        for (int sub = 0; sub < 2; ++sub)
#pragma unroll
            for (int ks = 0; ks < 4; ++ks)
                bq[sub * 4 + ks] = *(const us8*)(Wn + (ntile + sub * 16 + col) * CC + ks * 32 + quad * 8);

        __syncthreads();   // As[cur] ready — single barrier per tap (dbuf proof in R8 notes)

        // ---- MFMA: 32(M) x 32(N) wave tile, 4 K-steps of 32 ----
#pragma unroll
        for (int ks = 0; ks < 4; ++ks) {
            bf16x8 a0 = __builtin_bit_cast(bf16x8, *(const us8*)(&As[cur][mtile + col][ks * 32 + quad * 8]));
            bf16x8 a1 = __builtin_bit_cast(bf16x8, *(const us8*)(&As[cur][mtile + 16 + col][ks * 32 + quad * 8]));
            bf16x8 b0 = __builtin_bit_cast(bf16x8, bq[ks]);
            bf16x8 b1 = __builtin_bit_cast(bf16x8, bq[4 + ks]);
            acc[0][0] = __builtin_amdgcn_mfma_f32_16x16x32_bf16(a0, b0, acc[0][0], 0, 0, 0);
            acc[0][1] = __builtin_amdgcn_mfma_f32_16x16x32_bf16(a0, b1, acc[0][1], 0, 0, 0);
            acc[1][0] = __builtin_amdgcn_mfma_f32_16x16x32_bf16(a1, b0, acc[1][0], 0, 0, 0);
            acc[1][1] = __builtin_amdgcn_mfma_f32_16x16x32_bf16(a1, b1, acc[1][1], 0, 0, 0);
        }
        // no trailing barrier: next tap writes the OTHER As buffer; a wave can
        // only reach tap n+2 (same buffer) after barrier n+1, which orders it
        // after every wave's tap-n reads.
    }

    // ---- epilogue: C/D layout col=lane&15, row=quad*4+reg (HW-verified) ----
#pragma unroll
    for (int b = 0; b < 2; ++b) {
        int f = ntile + b * 16 + col;
        float bv = bias[f];
#pragma unroll
        for (int a = 0; a < 2; ++a) {
#pragma unroll
            for (int r = 0; r < 4; ++r) {
                int pr = pix0 + mtile + a * 16 + quad * 4 + r;
                out[(size_t)pr * FF + f] = acc[a][b][r] + bv;
            }
        }
    }
}

extern "C" void kernel_launch(void* const* d_in, const int* in_sizes, int n_in,
                              void* d_out, int out_size, void* d_ws, size_t ws_size,
                              hipStream_t stream) {
    const float* x    = (const float*)d_in[0];
    const float* off  = (const float*)d_in[1];
    const float* Wk   = (const float*)d_in[2];
    const float* bias = (const float*)d_in[3];
    float* out = (float*)d_out;
    unsigned short* Wt = (unsigned short*)d_ws;  // 9*128*128 bf16 = 294912 B

    wt_kernel<<<KN * 16, 256, 0, stream>>>(Wk, Wt);
    deform_kernel<<<(8 * HH * WW) / TM, NT, 0, stream>>>(x, off, Wt, bias, out);
}

// Round 9
// 127.742 us; speedup vs baseline: 1.0514x; 1.0058x over previous
//
#include <hip/hip_runtime.h>
#include <stdint.h>

#define KN 9
#define HH 64
#define WW 64
#define CC 128
#define FF 128
#define TM 64      // pixels per block (one full image row)
#define NT 512     // threads per block (8 waves: 4 producers + 4 consumers)
#define LDK 136    // padded LDS K-stride (bf16): 272B row -> conflict-free b128
#define DEPTH 3    // As ring depth (taps in flight)

typedef __bf16 bf16x8 __attribute__((ext_vector_type(8)));
typedef float f32x4 __attribute__((ext_vector_type(4)));
typedef unsigned short us8 __attribute__((ext_vector_type(8)));
typedef unsigned short us4 __attribute__((ext_vector_type(4)));

// Reference tap layout (verified R3): stack(meshgrid(ij)).reshape(-1,2) pairs
// the C-order flatten of (2,3,3) across the I/J boundary:
//   taps = (0,0)(0,1)(1,1)(2,2)(2,0)(1,2)(0,1)(2,0)(1,2)
__constant__ float c_init_i[KN] = {0.f,0.f,1.f,2.f,2.f,1.f,0.f,2.f,1.f};
__constant__ float c_init_j[KN] = {0.f,1.f,1.f,2.f,0.f,2.f,1.f,0.f,2.f};

static __device__ inline unsigned short f2bf(float f) {
    union { float f; unsigned u; } v; v.f = f;
    unsigned r = v.u + 0x7fffu + ((v.u >> 16) & 1u);  // RNE
    return (unsigned short)(r >> 16);
}

// Transpose + quantize W: (KN, C, F) fp32 -> Wt (KN, F, C) bf16.
// LDS 32x32 tile transpose: coalesced reads AND writes (R6-verified).
__global__ void wt_kernel(const float* __restrict__ Wk, unsigned short* __restrict__ Wt) {
    __shared__ unsigned short t[32][33];
    const int tid = threadIdx.x;
    const int n  = blockIdx.x >> 4;
    const int tf = blockIdx.x & 3;
    const int tc = (blockIdx.x >> 2) & 3;
    const int g  = tid >> 5;
    const int l  = tid & 31;
#pragma unroll
    for (int r = 0; r < 4; ++r) {
        int cl = g * 4 + r;
        t[cl][l] = f2bf(Wk[(n << 14) + ((tc * 32 + cl) << 7) + (tf * 32 + l)]);
    }
    __syncthreads();
#pragma unroll
    for (int r = 0; r < 4; ++r) {
        int fl = g * 4 + r;
        Wt[(n << 14) + ((tf * 32 + fl) << 7) + (tc * 32 + l)] = t[l][fl];
    }
}

__launch_bounds__(NT, 4)   // cap 128 VGPR; LDS caps residency at 2 blocks/CU
__global__ void deform_kernel(const float* __restrict__ xin,
                              const float* __restrict__ off,
                              const unsigned short* __restrict__ Wt,
                              const float* __restrict__ bias,
                              float* __restrict__ out) {
    __shared__ unsigned short As[DEPTH][TM][LDK];  // ring of deform tiles
    __shared__ float cY[TM][KN];
    __shared__ float cX[TM][KN];
    __shared__ int rdy[DEPTH];   // producer-wave completions per slot (monotonic)
    __shared__ int fin[DEPTH];   // consumer-wave completions per slot (monotonic)
    // 3*17408 + 2304 + 2304 + 24 = 56856 B -> 2 blocks/CU

    const int tid = threadIdx.x;
    // XCD swizzle (verified R5: FETCH 196->10.5 MB): image b -> XCD b.
    const int bb   = blockIdx.x & 7;
    const int hh   = blockIdx.x >> 3;
    const int pix0 = (bb << 12) + (hh << 6);

    if (tid < DEPTH) { rdy[tid] = 0; fin[tid] = 0; }

    for (int t = tid; t < TM * KN; t += NT) {
        int p = t & (TM - 1);
        int n = t >> 6;
        const float* op = off + (size_t)(pix0 + p) * (2 * KN) + 2 * n;
        float y = (float)(hh - 1) + c_init_i[n] + op[0];
        float x = (float)(p - 1) + c_init_j[n] + op[1];
        cY[p][n] = fminf(fmaxf(y, 0.f), 63.f);
        cX[p][n] = fminf(fmaxf(x, 0.f), 63.f);
    }
    __syncthreads();   // the ONLY workgroup barrier

    const int wave = tid >> 6;
    const int lane = tid & 63;
    const int quad = lane >> 4;
    const int col  = lane & 15;
    const float* bbase = xin + ((size_t)bb << 19);

    if (wave < 4) {
        // ================= PRODUCER: gather + interp -> As ring =============
        const int lgl = (wave << 6) + lane;   // 0..255
        auto issue = [&](int n, int u, float4* pf) {
            int i  = lgl + u * 256;
            int p  = i >> 5;
            int cg = (i & 31) * 4;
            float y = cY[p][n], x = cX[p][n];
            int y0 = (int)floorf(y), x0 = (int)floorf(x);
            int y1 = (int)ceilf(y),  x1 = (int)ceilf(x);
            pf[0] = *(const float4*)(bbase + ((((y0 << 6) + x0) << 7) + cg));
            pf[1] = *(const float4*)(bbase + ((((y1 << 6) + x0) << 7) + cg));
            pf[2] = *(const float4*)(bbase + ((((y0 << 6) + x1) << 7) + cg));
            pf[3] = *(const float4*)(bbase + ((((y1 << 6) + x1) << 7) + cg));
        };
        auto consume = [&](int n, int u, const float4* pf, int s) {
            int i  = lgl + u * 256;
            int p  = i >> 5;
            int cg = (i & 31) * 4;
            float y = cY[p][n], x = cX[p][n];
            float fy = y - floorf(y), fx = x - floorf(x);
            float r0, r1, r2, r3;
            { float vt = pf[0].x + (pf[1].x - pf[0].x) * fy; float vb = pf[2].x + (pf[3].x - pf[2].x) * fy; r0 = vt + (vb - vt) * fx; }
            { float vt = pf[0].y + (pf[1].y - pf[0].y) * fy; float vb = pf[2].y + (pf[3].y - pf[2].y) * fy; r1 = vt + (vb - vt) * fx; }
            { float vt = pf[0].z + (pf[1].z - pf[0].z) * fy; float vb = pf[2].z + (pf[3].z - pf[2].z) * fy; r2 = vt + (vb - vt) * fx; }
            { float vt = pf[0].w + (pf[1].w - pf[0].w) * fy; float vb = pf[2].w + (pf[3].w - pf[2].w) * fy; r3 = vt + (vb - vt) * fx; }
            us4 pk;
            pk.x = f2bf(r0); pk.y = f2bf(r1); pk.z = f2bf(r2); pk.w = f2bf(r3);
            *(us4*)&As[s][p][cg] = pk;
        };

        for (int n = 0; n < KN; ++n) {
            const int s = n % DEPTH;
            if (n >= DEPTH) {   // wait for slot's previous use to be drained
                const int tgt = 4 * (n / DEPTH);
                while (*(volatile int*)&fin[s] < tgt) __builtin_amdgcn_s_sleep(1);
                __threadfence_block();
            }
            // 8 units, 2-deep register rotation (barrier-free loop body)
            float4 A[4], B[4];
            issue(n, 0, A); issue(n, 1, B);
            consume(n, 0, A, s); issue(n, 2, A);
            consume(n, 1, B, s); issue(n, 3, B);
            consume(n, 2, A, s); issue(n, 4, A);
            consume(n, 3, B, s); issue(n, 5, B);
            consume(n, 4, A, s); issue(n, 6, A);
            consume(n, 5, B, s); issue(n, 7, B);
            consume(n, 6, A, s);
            consume(n, 7, B, s);
            __threadfence_block();            // drain As writes
            if (lane == 0) atomicAdd(&rdy[s], 1);
        }
    } else {
        // ================= CONSUMER: MFMA over the ring =====================
        const int cw  = wave - 4;
        const int mtb = (cw & 1) * 32;    // 32 pixels
        const int ntb = (cw >> 1) * 64;   // 64 filters
        f32x4 acc[2][4];
#pragma unroll
        for (int a = 0; a < 2; ++a)
#pragma unroll
            for (int b = 0; b < 4; ++b) acc[a][b] = (f32x4){0.f, 0.f, 0.f, 0.f};

        for (int n = 0; n < KN; ++n) {
            const int s = n % DEPTH;
            // B fragments from L2-resident Wt — independent of As readiness,
            // issued before the spin so they complete while waiting.
            us8 bq[16];
            const unsigned short* Wn = Wt + (n << 14);
#pragma unroll
            for (int b = 0; b < 4; ++b)
#pragma unroll
                for (int ks = 0; ks < 4; ++ks)
                    bq[b * 4 + ks] = *(const us8*)(Wn + (ntb + b * 16 + col) * CC + ks * 32 + quad * 8);

            const int tgt = 4 * (n / DEPTH + 1);
            while (*(volatile int*)&rdy[s] < tgt) __builtin_amdgcn_s_sleep(1);
            __threadfence_block();

#pragma unroll
            for (int ks = 0; ks < 4; ++ks) {
                bf16x8 a0 = __builtin_bit_cast(bf16x8, *(const us8*)(&As[s][mtb + col][ks * 32 + quad * 8]));
                bf16x8 a1 = __builtin_bit_cast(bf16x8, *(const us8*)(&As[s][mtb + 16 + col][ks * 32 + quad * 8]));
#pragma unroll
                for (int b = 0; b < 4; ++b) {
                    bf16x8 bf = __builtin_bit_cast(bf16x8, bq[b * 4 + ks]);
                    acc[0][b] = __builtin_amdgcn_mfma_f32_16x16x32_bf16(a0, bf, acc[0][b], 0, 0, 0);
                    acc[1][b] = __builtin_amdgcn_mfma_f32_16x16x32_bf16(a1, bf, acc[1][b], 0, 0, 0);
                }
            }
            __threadfence_block();            // As reads done before releasing slot
            if (lane == 0) atomicAdd(&fin[s], 1);
        }

        // ---- epilogue: C/D layout col=lane&15, row=quad*4+reg (HW-verified) ----
#pragma unroll
        for (int b = 0; b < 4; ++b) {
            int f = ntb + b * 16 + col;
            float bv = bias[f];
#pragma unroll
            for (int a = 0; a < 2; ++a) {
#pragma unroll
                for (int r = 0; r < 4; ++r) {
                    int pr = pix0 + mtb + a * 16 + quad * 4 + r;
                    out[(size_t)pr * FF + f] = acc[a][b][r] + bv;
                }
            }
        }
    }
}

extern "C" void kernel_launch(void* const* d_in, const int* in_sizes, int n_in,
                              void* d_out, int out_size, void* d_ws, size_t ws_size,
                              hipStream_t stream) {
    const float* x    = (const float*)d_in[0];
    const float* off  = (const float*)d_in[1];
    const float* Wk   = (const float*)d_in[2];
    const float* bias = (const float*)d_in[3];
    float* out = (float*)d_out;
    unsigned short* Wt = (unsigned short*)d_ws;  // 9*128*128 bf16 = 294912 B

    wt_kernel<<<KN * 16, 256, 0, stream>>>(Wk, Wt);
    deform_kernel<<<(8 * HH * WW) / TM, NT, 0, stream>>>(x, off, Wt, bias, out);
}

// Round 10
// 106.127 us; speedup vs baseline: 1.2656x; 1.2037x over previous
//
#include <hip/hip_runtime.h>
#include <stdint.h>

#define KN 9
#define HH 64
#define WW 64
#define CC 128
#define FF 128
#define TM 64      // pixels per block (one full image row)
#define NT 512     // threads per block (8 waves)
#define LDK 136    // padded LDS K-stride (bf16): 272B rows -> 4-way max on b128

typedef __bf16 bf16x8 __attribute__((ext_vector_type(8)));
typedef float f32x4 __attribute__((ext_vector_type(4)));
typedef unsigned short us8 __attribute__((ext_vector_type(8)));
typedef unsigned short us4 __attribute__((ext_vector_type(4)));

// Reference tap layout (verified R3): stack(meshgrid(ij)).reshape(-1,2) pairs
// the C-order flatten of (2,3,3) across the I/J boundary:
//   taps = (0,0)(0,1)(1,1)(2,2)(2,0)(1,2)(0,1)(2,0)(1,2)
__constant__ float c_init_i[KN] = {0.f,0.f,1.f,2.f,2.f,1.f,0.f,2.f,1.f};
__constant__ float c_init_j[KN] = {0.f,1.f,1.f,2.f,0.f,2.f,1.f,0.f,2.f};

static __device__ inline unsigned short f2bf(float f) {
    union { float f; unsigned u; } v; v.f = f;
    unsigned r = v.u + 0x7fffu + ((v.u >> 16) & 1u);  // RNE
    return (unsigned short)(r >> 16);
}
static __device__ inline float bf2f(unsigned short h) {
    union { unsigned u; float f; } v; v.u = ((unsigned)h) << 16;
    return v.f;
}

// Quantize x: (B,H,W,C) fp32 -> bf16. Streaming, ~25 MB.
__global__ void xq_kernel(const float* __restrict__ x, unsigned short* __restrict__ xq) {
    int idx = blockIdx.x * 256 + threadIdx.x;      // 4 elems per thread
    const float4 v = ((const float4*)x)[idx];
    us4 o;
    o.x = f2bf(v.x); o.y = f2bf(v.y); o.z = f2bf(v.z); o.w = f2bf(v.w);
    ((us4*)xq)[idx] = o;
}

// Transpose + quantize W: (KN, C, F) fp32 -> Wt (KN, F, C) bf16.
// LDS 32x32 tile transpose: coalesced reads AND writes (R6-verified).
__global__ void wt_kernel(const float* __restrict__ Wk, unsigned short* __restrict__ Wt) {
    __shared__ unsigned short t[32][33];
    const int tid = threadIdx.x;
    const int n  = blockIdx.x >> 4;
    const int tf = blockIdx.x & 3;
    const int tc = (blockIdx.x >> 2) & 3;
    const int g  = tid >> 5;
    const int l  = tid & 31;
#pragma unroll
    for (int r = 0; r < 4; ++r) {
        int cl = g * 4 + r;
        t[cl][l] = f2bf(Wk[(n << 14) + ((tc * 32 + cl) << 7) + (tf * 32 + l)]);
    }
    __syncthreads();
#pragma unroll
    for (int r = 0; r < 4; ++r) {
        int fl = g * 4 + r;
        Wt[(n << 14) + ((tf * 32 + fl) << 7) + (tc * 32 + l)] = t[l][fl];
    }
}

__launch_bounds__(NT, 4)
__global__ void deform_kernel(const unsigned short* __restrict__ xq,
                              const float* __restrict__ off,
                              const unsigned short* __restrict__ Wt,
                              const float* __restrict__ bias,
                              float* __restrict__ out) {
    __shared__ unsigned short As[TM][LDK];   // deform tile, bf16, M x K
    __shared__ unsigned short Bt[FF][LDK];   // W tap, bf16, N x K (B^T layout)
    __shared__ float cY[TM][KN];
    __shared__ float cX[TM][KN];
    // 17408 + 34816 + 2304 + 2304 = 56832 B -> 2 blocks/CU  (R6-proven shape)

    const int tid = threadIdx.x;
    // XCD swizzle (verified R5: FETCH 196->10.5 MB): image b -> XCD b.
    const int bb   = blockIdx.x & 7;
    const int hh   = blockIdx.x >> 3;
    const int pix0 = (bb << 12) + (hh << 6);

    for (int t = tid; t < TM * KN; t += NT) {
        int p = t & (TM - 1);
        int n = t >> 6;
        const float* op = off + (size_t)(pix0 + p) * (2 * KN) + 2 * n;
        float y = (float)(hh - 1) + c_init_i[n] + op[0];
        float x = (float)(p - 1) + c_init_j[n] + op[1];
        cY[p][n] = fminf(fmaxf(y, 0.f), 63.f);
        cX[p][n] = fminf(fmaxf(x, 0.f), 63.f);
    }
    __syncthreads();

    const int wave = tid >> 6;
    const int lane = tid & 63;
    const int quad = lane >> 4;
    const int col  = lane & 15;
    const int mtile = (wave & 1) * 32;   // 2 M-supertiles of 32 pixels
    const int ntile = (wave >> 1) * 32;  // 4 N-supertiles of 32 filters

    f32x4 acc[2][2];
#pragma unroll
    for (int a = 0; a < 2; ++a)
#pragma unroll
        for (int b = 0; b < 2; ++b) acc[a][b] = (f32x4){0.f, 0.f, 0.f, 0.f};

    const unsigned short* bbase = xq + ((size_t)bb << 19);  // b * 64*64*128

    // issue the 4 bf16 corner loads (us8 = 8 channels) for unit k of tap n
    auto issueA = [&](int n, int k, us8* pc) {
        int i  = tid + k * NT;       // 1024 units: 64 pixels x 16 ch-groups
        int p  = i >> 4;
        int cg = (i & 15) * 8;
        float y = cY[p][n], x = cX[p][n];
        int y0 = (int)floorf(y), x0 = (int)floorf(x);
        int y1 = (int)ceilf(y),  x1 = (int)ceilf(x);
        pc[0] = *(const us8*)(bbase + ((((y0 << 6) + x0) << 7) + cg));  // lt
        pc[1] = *(const us8*)(bbase + ((((y1 << 6) + x0) << 7) + cg));  // rt
        pc[2] = *(const us8*)(bbase + ((((y0 << 6) + x1) << 7) + cg));  // lb
        pc[3] = *(const us8*)(bbase + ((((y1 << 6) + x1) << 7) + cg));  // rb
    };
    // interp 8 channels fp32, pack to As (write = 16B/lane, conflict-free)
    auto consumeA = [&](int n, int k, const us8* pc) {
        int i  = tid + k * NT;
        int p  = i >> 4;
        int cg = (i & 15) * 8;
        float y = cY[p][n], x = cX[p][n];
        float fy = y - floorf(y), fx = x - floorf(x);
        us8 pk;
#pragma unroll
        for (int c = 0; c < 8; ++c) {
            float vlt = bf2f(pc[0][c]), vrt = bf2f(pc[1][c]);
            float vlb = bf2f(pc[2][c]), vrb = bf2f(pc[3][c]);
            float vt = vlt + (vrt - vlt) * fy;
            float vb = vlb + (vrb - vlb) * fy;
            pk[c] = f2bf(vt + (vb - vt) * fx);
        }
        *(us8*)&As[p][cg] = pk;
    };

    for (int n = 0; n < KN; ++n) {
        // ---- stage Bt: contiguous copy of Wt[n] (N x K, bf16) ----
        const unsigned short* Wn = Wt + n * (CC * FF);
#pragma unroll
        for (int k = 0; k < 4; ++k) {
            int i2 = tid + k * NT;
            *(us8*)&Bt[i2 >> 4][(i2 & 15) * 8] = *(const us8*)(Wn + (i2 >> 4) * CC + (i2 & 15) * 8);
        }
        // ---- gather: 2 units/thread, both issued before first consume ----
        us8 u0[4], u1[4];
        issueA(n, 0, u0);
        issueA(n, 1, u1);
        consumeA(n, 0, u0);
        consumeA(n, 1, u1);
        __syncthreads();   // As/Bt ready

        // ---- MFMA: 32(M) x 32(N) wave tile, 4 K-steps of 32 ----
#pragma unroll
        for (int ks = 0; ks < 4; ++ks) {
            bf16x8 a0 = __builtin_bit_cast(bf16x8, *(const us8*)(&As[mtile + col][ks * 32 + quad * 8]));
            bf16x8 a1 = __builtin_bit_cast(bf16x8, *(const us8*)(&As[mtile + 16 + col][ks * 32 + quad * 8]));
            bf16x8 b0 = __builtin_bit_cast(bf16x8, *(const us8*)(&Bt[ntile + col][ks * 32 + quad * 8]));
            bf16x8 b1 = __builtin_bit_cast(bf16x8, *(const us8*)(&Bt[ntile + 16 + col][ks * 32 + quad * 8]));
            acc[0][0] = __builtin_amdgcn_mfma_f32_16x16x32_bf16(a0, b0, acc[0][0], 0, 0, 0);
            acc[0][1] = __builtin_amdgcn_mfma_f32_16x16x32_bf16(a0, b1, acc[0][1], 0, 0, 0);
            acc[1][0] = __builtin_amdgcn_mfma_f32_16x16x32_bf16(a1, b0, acc[1][0], 0, 0, 0);
            acc[1][1] = __builtin_amdgcn_mfma_f32_16x16x32_bf16(a1, b1, acc[1][1], 0, 0, 0);
        }
        __syncthreads();   // protect As/Bt overwrite next tap
    }

    // ---- epilogue: C/D layout col=lane&15, row=quad*4+reg (HW-verified) ----
#pragma unroll
    for (int b = 0; b < 2; ++b) {
        int f = ntile + b * 16 + col;
        float bv = bias[f];
#pragma unroll
        for (int a = 0; a < 2; ++a) {
#pragma unroll
            for (int r = 0; r < 4; ++r) {
                int pr = pix0 + mtile + a * 16 + quad * 4 + r;
                out[(size_t)pr * FF + f] = acc[a][b][r] + bv;
            }
        }
    }
}

extern "C" void kernel_launch(void* const* d_in, const int* in_sizes, int n_in,
                              void* d_out, int out_size, void* d_ws, size_t ws_size,
                              hipStream_t stream) {
    const float* x    = (const float*)d_in[0];
    const float* off  = (const float*)d_in[1];
    const float* Wk   = (const float*)d_in[2];
    const float* bias = (const float*)d_in[3];
    float* out = (float*)d_out;
    unsigned short* Wt = (unsigned short*)d_ws;              // 294912 B
    unsigned short* xq = (unsigned short*)d_ws + (KN * CC * FF);  // 8.4 MB bf16 x

    wt_kernel<<<KN * 16, 256, 0, stream>>>(Wk, Wt);
    xq_kernel<<<(8 * HH * WW * CC) / 4 / 256, 256, 0, stream>>>(x, xq);
    deform_kernel<<<(8 * HH * WW) / TM, NT, 0, stream>>>(xq, off, Wt, bias, out);
}